// Round 5
// baseline (321.542 us; speedup 1.0000x reference)
//
#include <hip/hip_runtime.h>
#include <hip/hip_bf16.h>

#define RR 100
#define MID 256
#define NN 384
#define KP 128   // rank padded to 128 (zeros in r=100..127)

typedef __attribute__((ext_vector_type(8))) __bf16 bf16x8;
typedef __attribute__((ext_vector_type(4))) float floatx4;
typedef unsigned short ushort_t;

// Swizzled LDS offset (elements) for row-major [128][KP] bf16 tiles stored as
// 16 chunks of 8 bf16 per row; chunk index XOR'd with (row&15) so that
// MFMA fragment reads (16 rows x same chunk) spread across all 32 banks.
#define SW(row, ch) ((((row) << 7)) + ((((ch) ^ ((row) & 15))) << 3))

__device__ __forceinline__ ushort_t f2bf(float f) {
  __hip_bfloat16 h = __float2bfloat16(f);
  return __builtin_bit_cast(ushort_t, h);
}

// ---------------- Factor nets (all three in one launch) ----------------
// blockIdx.x = row i (0..383), blockIdx.y = net (0=A, 1=B, 2=C).
// A,B written as fp32 [384][128] (pad zeros); C written as bf16 [384][128].
__global__ __launch_bounds__(256) void factors_kernel(
    const float* __restrict__ xA, const float* __restrict__ xB,
    const float* __restrict__ xC,
    const float* __restrict__ AW1, const float* __restrict__ Ab1,
    const float* __restrict__ AW2, const float* __restrict__ Ab2,
    const float* __restrict__ BW1, const float* __restrict__ Bb1,
    const float* __restrict__ BW2, const float* __restrict__ Bb2,
    const float* __restrict__ CW1, const float* __restrict__ Cb1,
    const float* __restrict__ CW2, const float* __restrict__ Cb2,
    const float* __restrict__ CW3, const float* __restrict__ Cb3,
    float* __restrict__ Af, float* __restrict__ Bf,
    ushort_t* __restrict__ Cbf) {
  __shared__ float h[MID];
  __shared__ float h2[MID];
  const int i = blockIdx.x;
  const int net = blockIdx.y;
  const int t = threadIdx.x;

  const float* x  = (net == 0) ? xA  : (net == 1) ? xB  : xC;
  const float* W1 = (net == 0) ? AW1 : (net == 1) ? BW1 : CW1;
  const float* b1 = (net == 0) ? Ab1 : (net == 1) ? Bb1 : Cb1;

  const float xv = x[i];
  h[t] = sinf(1.5f * (xv * W1[t] + b1[t]));
  __syncthreads();

  const float* hlast = h;
  if (net == 2) {  // block-uniform branch
    float acc = Cb2[t];
    const float* __restrict__ w = &CW2[t * MID];
#pragma unroll 4
    for (int m = 0; m < MID; m += 4) {
      const float4 wv = *(const float4*)&w[m];
      const float4 hv = *(const float4*)&h[m];
      acc += hv.x * wv.x;
      acc += hv.y * wv.y;
      acc += hv.z * wv.z;
      acc += hv.w * wv.w;
    }
    h2[t] = sinf(1.5f * acc);
    __syncthreads();
    hlast = h2;
  }

  const float* W2 = (net == 0) ? AW2 : (net == 1) ? BW2 : CW3;
  const float* b2 = (net == 0) ? Ab2 : (net == 1) ? Bb2 : Cb3;

  if (t < KP) {
    float v = 0.0f;
    if (t < RR) {
      float acc = b2[t];
      const float* __restrict__ w = &W2[t * MID];
#pragma unroll 4
      for (int m = 0; m < MID; m += 4) {
        const float4 wv = *(const float4*)&w[m];
        const float4 hv = *(const float4*)&hlast[m];
        acc += hv.x * wv.x;
        acc += hv.y * wv.y;
        acc += hv.z * wv.z;
        acc += hv.w * wv.w;
      }
      v = acc;
    }
    if (net == 0)      Af[i * KP + t] = v;
    else if (net == 1) Bf[i * KP + t] = v;
    else               Cbf[i * KP + t] = f2bf(v);
  }
}

// ---------------- CP contraction via bf16 MFMA ----------------
// R3 structure EXACTLY (both tiles staged in LDS, one barrier, occ 2,
// swapped MFMA operands, 16 dwordx4 stores) with ONE change: the epilogue
// stores are NON-TEMPORAL. Theory: the 226.5 MB output stream flowing
// through L2 continuously evicts the 480 KB operand arrays (L2-thrash),
// forcing every block's staging reads to L3 (~600 cy). NT stores bypass
// L2 allocation; each store instruction presents 16 complete 64 B
// segments (= HBM burst size), so there is no granule penalty.
__global__ __launch_bounds__(256, 2) void cp_mfma(
    const float* __restrict__ Af, const float* __restrict__ Bf,
    const ushort_t* __restrict__ Cbf, float* __restrict__ out) {
  __shared__ ushort_t Wt[128 * KP];  // 32 KB
  __shared__ ushort_t Ct[128 * KP];  // 32 KB

  const int i  = blockIdx.z;
  const int j0 = blockIdx.y * 128;
  const int k0 = blockIdx.x * 128;
  const int t  = threadIdx.x;

  // ---- stage C tile: plain bf16 copy into swizzled LDS (16B chunks) ----
#pragma unroll
  for (int it = 0; it < 8; ++it) {
    const int idx = t + 256 * it;
    const int row = idx >> 4;
    const int ch  = idx & 15;
    *(uint4*)&Ct[SW(row, ch)] =
        *(const uint4*)&Cbf[(size_t)(k0 + row) * KP + ch * 8];
  }

  // ---- compute W tile: 2 threads per row, 64 r's each ----
  {
    const int jx = t >> 1;
    const int hh = t & 1;
    const float* __restrict__ arow = Af + (size_t)i * KP + hh * 64;
    const float* __restrict__ brow = Bf + (size_t)(j0 + jx) * KP + hh * 64;
#pragma unroll
    for (int c = 0; c < 8; ++c) {
      const float4 a0 = *(const float4*)(arow + c * 8);
      const float4 a1 = *(const float4*)(arow + c * 8 + 4);
      const float4 b0 = *(const float4*)(brow + c * 8);
      const float4 b1 = *(const float4*)(brow + c * 8 + 4);
      uint4 wv;
      wv.x = (unsigned)f2bf(a0.x * b0.x) | ((unsigned)f2bf(a0.y * b0.y) << 16);
      wv.y = (unsigned)f2bf(a0.z * b0.z) | ((unsigned)f2bf(a0.w * b0.w) << 16);
      wv.z = (unsigned)f2bf(a1.x * b1.x) | ((unsigned)f2bf(a1.y * b1.y) << 16);
      wv.w = (unsigned)f2bf(a1.z * b1.z) | ((unsigned)f2bf(a1.w * b1.w) << 16);
      *(uint4*)&Wt[SW(jx, hh * 8 + c)] = wv;
    }
  }
  __syncthreads();

  // ---- MFMA main loop ----
  const int lane = t & 63;
  const int w    = t >> 6;
  const int wj   = (w & 1) * 64;
  const int wk   = (w >> 1) * 64;
  const int m16  = lane & 15;
  const int g    = lane >> 4;

  // acc[kf][jf]: D col = j (m16), D row = k (g*4 + reg)
  floatx4 acc[4][4];
#pragma unroll
  for (int kf = 0; kf < 4; ++kf)
#pragma unroll
    for (int jf = 0; jf < 4; ++jf) acc[kf][jf] = (floatx4)0.0f;

#pragma unroll
  for (int ks = 0; ks < 4; ++ks) {
    bf16x8 cf[4], wfr[4];
#pragma unroll
    for (int f = 0; f < 4; ++f) {
      cf[f]  = *(const bf16x8*)&Ct[SW(wk + f * 16 + m16, ks * 4 + g)];
      wfr[f] = *(const bf16x8*)&Wt[SW(wj + f * 16 + m16, ks * 4 + g)];
    }
#pragma unroll
    for (int jf = 0; jf < 4; ++jf)
#pragma unroll
      for (int kf = 0; kf < 4; ++kf)
        acc[kf][jf] = __builtin_amdgcn_mfma_f32_16x16x32_bf16(
            cf[kf], wfr[jf], acc[kf][jf], 0, 0, 0);
  }

  // ---- epilogue: lane owns out[i, j0+wj+jf*16+m16, k0+wk+kf*16+g*4 .. +3] ----
  const size_t ibase = (size_t)i * NN * NN;
#pragma unroll
  for (int kf = 0; kf < 4; ++kf) {
    const int k = k0 + wk + kf * 16 + g * 4;
#pragma unroll
    for (int jf = 0; jf < 4; ++jf) {
      const int j = j0 + wj + jf * 16 + m16;
      __builtin_nontemporal_store(
          acc[kf][jf], (floatx4*)&out[ibase + (size_t)j * NN + k]);
    }
  }
}

extern "C" void kernel_launch(void* const* d_in, const int* in_sizes, int n_in,
                              void* d_out, int out_size, void* d_ws, size_t ws_size,
                              hipStream_t stream) {
  const float* A_input = (const float*)d_in[0];
  const float* B_input = (const float*)d_in[1];
  const float* C_input = (const float*)d_in[2];
  const float* A_W1 = (const float*)d_in[3];
  const float* A_b1 = (const float*)d_in[4];
  const float* A_W2 = (const float*)d_in[5];
  const float* A_b2 = (const float*)d_in[6];
  const float* B_W1 = (const float*)d_in[7];
  const float* B_b1 = (const float*)d_in[8];
  const float* B_W2 = (const float*)d_in[9];
  const float* B_b2 = (const float*)d_in[10];
  const float* C_W1 = (const float*)d_in[11];
  const float* C_b1 = (const float*)d_in[12];
  const float* C_W2 = (const float*)d_in[13];
  const float* C_b2 = (const float*)d_in[14];
  const float* C_W3 = (const float*)d_in[15];
  const float* C_b3 = (const float*)d_in[16];

  // ws layout: Af fp32 [384][128] | Bf fp32 [384][128] | Cbf bf16 [384][128]
  float* Af = (float*)d_ws;                       // 196,608 B
  float* Bf = Af + NN * KP;                       // 196,608 B
  ushort_t* Cbf = (ushort_t*)(Bf + NN * KP);      //  98,304 B  (total 480 KB)

  dim3 fgrid(NN, 3);
  factors_kernel<<<fgrid, 256, 0, stream>>>(
      A_input, B_input, C_input,
      A_W1, A_b1, A_W2, A_b2,
      B_W1, B_b1, B_W2, B_b2,
      C_W1, C_b1, C_W2, C_b2, C_W3, C_b3,
      Af, Bf, Cbf);

  dim3 grid(NN / 128, NN / 128, NN);  // (k-tiles, j-tiles, i)
  cp_mfma<<<grid, 256, 0, stream>>>(Af, Bf, Cbf, (float*)d_out);
}

// Round 6
// 321.129 us; speedup vs baseline: 1.0013x; 1.0013x over previous
//
#include <hip/hip_runtime.h>
#include <hip/hip_bf16.h>

#define RR 100
#define MID 256
#define NN 384
#define KP 128   // rank padded to 128 (zeros in r=100..127)

typedef __attribute__((ext_vector_type(8))) __bf16 bf16x8;
typedef __attribute__((ext_vector_type(4))) float floatx4;
typedef unsigned short ushort_t;

// Swizzled LDS offset (elements) for row-major [rows][KP] bf16 tiles stored as
// 16 chunks of 8 bf16 per row; chunk index XOR'd with (row&15) so that
// MFMA fragment reads (16 rows x same chunk) spread across all 32 banks.
#define SW(row, ch) ((((row) << 7)) + ((((ch) ^ ((row) & 15))) << 3))

__device__ __forceinline__ ushort_t f2bf(float f) {
  __hip_bfloat16 h = __float2bfloat16(f);
  return __builtin_bit_cast(ushort_t, h);
}

// ---------------- Factor nets (all three in one launch) ----------------
// blockIdx.x = row i (0..383), blockIdx.y = net (0=A, 1=B, 2=C).
// A,B written as fp32 [384][128] (pad zeros); C written as bf16 [384][128].
__global__ __launch_bounds__(256) void factors_kernel(
    const float* __restrict__ xA, const float* __restrict__ xB,
    const float* __restrict__ xC,
    const float* __restrict__ AW1, const float* __restrict__ Ab1,
    const float* __restrict__ AW2, const float* __restrict__ Ab2,
    const float* __restrict__ BW1, const float* __restrict__ Bb1,
    const float* __restrict__ BW2, const float* __restrict__ Bb2,
    const float* __restrict__ CW1, const float* __restrict__ Cb1,
    const float* __restrict__ CW2, const float* __restrict__ Cb2,
    const float* __restrict__ CW3, const float* __restrict__ Cb3,
    float* __restrict__ Af, float* __restrict__ Bf,
    ushort_t* __restrict__ Cbf) {
  __shared__ float h[MID];
  __shared__ float h2[MID];
  const int i = blockIdx.x;
  const int net = blockIdx.y;
  const int t = threadIdx.x;

  const float* x  = (net == 0) ? xA  : (net == 1) ? xB  : xC;
  const float* W1 = (net == 0) ? AW1 : (net == 1) ? BW1 : CW1;
  const float* b1 = (net == 0) ? Ab1 : (net == 1) ? Bb1 : Cb1;

  const float xv = x[i];
  h[t] = sinf(1.5f * (xv * W1[t] + b1[t]));
  __syncthreads();

  const float* hlast = h;
  if (net == 2) {  // block-uniform branch
    float acc = Cb2[t];
    const float* __restrict__ w = &CW2[t * MID];
#pragma unroll 4
    for (int m = 0; m < MID; m += 4) {
      const float4 wv = *(const float4*)&w[m];
      const float4 hv = *(const float4*)&h[m];
      acc += hv.x * wv.x;
      acc += hv.y * wv.y;
      acc += hv.z * wv.z;
      acc += hv.w * wv.w;
    }
    h2[t] = sinf(1.5f * acc);
    __syncthreads();
    hlast = h2;
  }

  const float* W2 = (net == 0) ? AW2 : (net == 1) ? BW2 : CW3;
  const float* b2 = (net == 0) ? Ab2 : (net == 1) ? Bb2 : Cb3;

  if (t < KP) {
    float v = 0.0f;
    if (t < RR) {
      float acc = b2[t];
      const float* __restrict__ w = &W2[t * MID];
#pragma unroll 4
      for (int m = 0; m < MID; m += 4) {
        const float4 wv = *(const float4*)&w[m];
        const float4 hv = *(const float4*)&hlast[m];
        acc += hv.x * wv.x;
        acc += hv.y * wv.y;
        acc += hv.z * wv.z;
        acc += hv.w * wv.w;
      }
      v = acc;
    }
    if (net == 0)      Af[i * KP + t] = v;
    else if (net == 1) Bf[i * KP + t] = v;
    else               Cbf[i * KP + t] = f2bf(v);
  }
}

// ---------------- CP contraction via bf16 MFMA ----------------
// R3 champion-structure with the j-tile HALVED (block = 64j x 128k) so
// LDS = 16 KB (Wt) + 32 KB (Ct) = 48 KB -> 3 blocks/CU (was 2 at 64 KB).
// Theory: phase-structured blocks (stage -> barrier -> MFMA -> stores)
// at occ 2 leave the HBM write pipe idle during stage/MFMA; a third
// resident block fills those gaps. All access patterns preserved:
// coalesced staging, swizzled conflict-free ds_read_b128, swapped-operand
// MFMA with full-line dwordx4 (plain, L2-allocating) stores.
__global__ __launch_bounds__(256, 3) void cp_mfma(
    const float* __restrict__ Af, const float* __restrict__ Bf,
    const ushort_t* __restrict__ Cbf, float* __restrict__ out) {
  __shared__ ushort_t Wt[64 * KP];    // 16 KB
  __shared__ ushort_t Ct[128 * KP];   // 32 KB

  const int i  = blockIdx.z;
  const int j0 = blockIdx.y * 64;
  const int k0 = blockIdx.x * 128;
  const int t  = threadIdx.x;

  // ---- stage C tile: plain bf16 copy into swizzled LDS (16B chunks) ----
#pragma unroll
  for (int it = 0; it < 8; ++it) {
    const int idx = t + 256 * it;
    const int row = idx >> 4;
    const int ch  = idx & 15;
    *(uint4*)&Ct[SW(row, ch)] =
        *(const uint4*)&Cbf[(size_t)(k0 + row) * KP + ch * 8];
  }

  // ---- compute W tile (64 rows): 4 threads per row, 32 r's each ----
  {
    const int jx = t >> 2;
    const int q  = t & 3;
    const float* __restrict__ arow = Af + (size_t)i * KP + q * 32;
    const float* __restrict__ brow = Bf + (size_t)(j0 + jx) * KP + q * 32;
#pragma unroll
    for (int c = 0; c < 4; ++c) {
      const float4 a0 = *(const float4*)(arow + c * 8);
      const float4 a1 = *(const float4*)(arow + c * 8 + 4);
      const float4 b0 = *(const float4*)(brow + c * 8);
      const float4 b1 = *(const float4*)(brow + c * 8 + 4);
      uint4 wv;
      wv.x = (unsigned)f2bf(a0.x * b0.x) | ((unsigned)f2bf(a0.y * b0.y) << 16);
      wv.y = (unsigned)f2bf(a0.z * b0.z) | ((unsigned)f2bf(a0.w * b0.w) << 16);
      wv.z = (unsigned)f2bf(a1.x * b1.x) | ((unsigned)f2bf(a1.y * b1.y) << 16);
      wv.w = (unsigned)f2bf(a1.z * b1.z) | ((unsigned)f2bf(a1.w * b1.w) << 16);
      *(uint4*)&Wt[SW(jx, q * 4 + c)] = wv;
    }
  }
  __syncthreads();

  // ---- MFMA main loop: wave owns 32j x 64k ----
  const int lane = t & 63;
  const int w    = t >> 6;
  const int wj   = (w & 1) * 32;
  const int wk   = (w >> 1) * 64;
  const int m16  = lane & 15;
  const int g    = lane >> 4;

  // acc[kf][jf]: D col = j (m16), D row = k (g*4 + reg)
  floatx4 acc[4][2];
#pragma unroll
  for (int kf = 0; kf < 4; ++kf)
#pragma unroll
    for (int jf = 0; jf < 2; ++jf) acc[kf][jf] = (floatx4)0.0f;

#pragma unroll
  for (int ks = 0; ks < 4; ++ks) {
    bf16x8 cf[4], wfr[2];
#pragma unroll
    for (int kf = 0; kf < 4; ++kf)
      cf[kf] = *(const bf16x8*)&Ct[SW(wk + kf * 16 + m16, ks * 4 + g)];
#pragma unroll
    for (int jf = 0; jf < 2; ++jf)
      wfr[jf] = *(const bf16x8*)&Wt[SW(wj + jf * 16 + m16, ks * 4 + g)];
#pragma unroll
    for (int jf = 0; jf < 2; ++jf)
#pragma unroll
      for (int kf = 0; kf < 4; ++kf)
        acc[kf][jf] = __builtin_amdgcn_mfma_f32_16x16x32_bf16(
            cf[kf], wfr[jf], acc[kf][jf], 0, 0, 0);
  }

  // ---- epilogue: lane owns out[i, j0+wj+jf*16+m16, k0+wk+kf*16+g*4 .. +3] ----
  const size_t ibase = (size_t)i * NN * NN;
#pragma unroll
  for (int kf = 0; kf < 4; ++kf) {
    const int k = k0 + wk + kf * 16 + g * 4;
#pragma unroll
    for (int jf = 0; jf < 2; ++jf) {
      const int j = j0 + wj + jf * 16 + m16;
      *(floatx4*)&out[ibase + (size_t)j * NN + k] = acc[kf][jf];
    }
  }
}

extern "C" void kernel_launch(void* const* d_in, const int* in_sizes, int n_in,
                              void* d_out, int out_size, void* d_ws, size_t ws_size,
                              hipStream_t stream) {
  const float* A_input = (const float*)d_in[0];
  const float* B_input = (const float*)d_in[1];
  const float* C_input = (const float*)d_in[2];
  const float* A_W1 = (const float*)d_in[3];
  const float* A_b1 = (const float*)d_in[4];
  const float* A_W2 = (const float*)d_in[5];
  const float* A_b2 = (const float*)d_in[6];
  const float* B_W1 = (const float*)d_in[7];
  const float* B_b1 = (const float*)d_in[8];
  const float* B_W2 = (const float*)d_in[9];
  const float* B_b2 = (const float*)d_in[10];
  const float* C_W1 = (const float*)d_in[11];
  const float* C_b1 = (const float*)d_in[12];
  const float* C_W2 = (const float*)d_in[13];
  const float* C_b2 = (const float*)d_in[14];
  const float* C_W3 = (const float*)d_in[15];
  const float* C_b3 = (const float*)d_in[16];

  // ws layout: Af fp32 [384][128] | Bf fp32 [384][128] | Cbf bf16 [384][128]
  float* Af = (float*)d_ws;                       // 196,608 B
  float* Bf = Af + NN * KP;                       // 196,608 B
  ushort_t* Cbf = (ushort_t*)(Bf + NN * KP);      //  98,304 B  (total 480 KB)

  dim3 fgrid(NN, 3);
  factors_kernel<<<fgrid, 256, 0, stream>>>(
      A_input, B_input, C_input,
      A_W1, A_b1, A_W2, A_b2,
      B_W1, B_b1, B_W2, B_b2,
      C_W1, C_b1, C_W2, C_b2, C_W3, C_b3,
      Af, Bf, Cbf);

  dim3 grid(NN / 128, NN / 64, NN);  // (k-tiles, j-tiles, i)
  cp_mfma<<<grid, 256, 0, stream>>>(Af, Bf, Cbf, (float*)d_out);
}

// Round 7
// 292.844 us; speedup vs baseline: 1.0980x; 1.0966x over previous
//
#include <hip/hip_runtime.h>
#include <hip/hip_bf16.h>

#define RR 100
#define MID 256
#define NN 384
#define KP 128   // rank padded to 128 (zeros in r=100..127)

typedef __attribute__((ext_vector_type(8))) __bf16 bf16x8;
typedef __attribute__((ext_vector_type(4))) float floatx4;
typedef unsigned short ushort_t;

// Swizzled LDS offset (elements) for row-major [rows][KP] bf16 tiles stored as
// 16 chunks of 8 bf16 per row; chunk index XOR'd with (row&15) so that
// MFMA fragment reads (16 rows x same chunk) spread across all 32 banks.
#define SW(row, ch) ((((row) << 7)) + ((((ch) ^ ((row) & 15))) << 3))

__device__ __forceinline__ ushort_t f2bf(float f) {
  __hip_bfloat16 h = __float2bfloat16(f);
  return __builtin_bit_cast(ushort_t, h);
}

// ---------------- Factor nets (all three in one launch) ----------------
// blockIdx.x = row i (0..383), blockIdx.y = net (0=A, 1=B, 2=C).
// A,B written as fp32 [384][128] (pad zeros); C written as bf16 [384][128].
__global__ __launch_bounds__(256) void factors_kernel(
    const float* __restrict__ xA, const float* __restrict__ xB,
    const float* __restrict__ xC,
    const float* __restrict__ AW1, const float* __restrict__ Ab1,
    const float* __restrict__ AW2, const float* __restrict__ Ab2,
    const float* __restrict__ BW1, const float* __restrict__ Bb1,
    const float* __restrict__ BW2, const float* __restrict__ Bb2,
    const float* __restrict__ CW1, const float* __restrict__ Cb1,
    const float* __restrict__ CW2, const float* __restrict__ Cb2,
    const float* __restrict__ CW3, const float* __restrict__ Cb3,
    float* __restrict__ Af, float* __restrict__ Bf,
    ushort_t* __restrict__ Cbf) {
  __shared__ float h[MID];
  __shared__ float h2[MID];
  const int i = blockIdx.x;
  const int net = blockIdx.y;
  const int t = threadIdx.x;

  const float* x  = (net == 0) ? xA  : (net == 1) ? xB  : xC;
  const float* W1 = (net == 0) ? AW1 : (net == 1) ? BW1 : CW1;
  const float* b1 = (net == 0) ? Ab1 : (net == 1) ? Bb1 : Cb1;

  const float xv = x[i];
  h[t] = sinf(1.5f * (xv * W1[t] + b1[t]));
  __syncthreads();

  const float* hlast = h;
  if (net == 2) {  // block-uniform branch
    float acc = Cb2[t];
    const float* __restrict__ w = &CW2[t * MID];
#pragma unroll 4
    for (int m = 0; m < MID; m += 4) {
      const float4 wv = *(const float4*)&w[m];
      const float4 hv = *(const float4*)&h[m];
      acc += hv.x * wv.x;
      acc += hv.y * wv.y;
      acc += hv.z * wv.z;
      acc += hv.w * wv.w;
    }
    h2[t] = sinf(1.5f * acc);
    __syncthreads();
    hlast = h2;
  }

  const float* W2 = (net == 0) ? AW2 : (net == 1) ? BW2 : CW3;
  const float* b2 = (net == 0) ? Ab2 : (net == 1) ? Bb2 : Cb3;

  if (t < KP) {
    float v = 0.0f;
    if (t < RR) {
      float acc = b2[t];
      const float* __restrict__ w = &W2[t * MID];
#pragma unroll 4
      for (int m = 0; m < MID; m += 4) {
        const float4 wv = *(const float4*)&w[m];
        const float4 hv = *(const float4*)&hlast[m];
        acc += hv.x * wv.x;
        acc += hv.y * wv.y;
        acc += hv.z * wv.z;
        acc += hv.w * wv.w;
      }
      v = acc;
    }
    if (net == 0)      Af[i * KP + t] = v;
    else if (net == 1) Bf[i * KP + t] = v;
    else               Cbf[i * KP + t] = f2bf(v);
  }
}

// ---------------- CP contraction via bf16 MFMA ----------------
// CONTIGUOUS-WRITE restructure: block = (i, j0) computes the full-k slab
// out[i, j0:j0+64, 0:384] -- a single contiguous 96 KB span of the output
// (j-rows are adjacent in memory when k is full-extent). The 3 C k-tiles
// cycle through one 32 KB LDS buffer; the 64-row W band is folded once
// (16 KB). Bijective XCD swizzle (2304 % 8 == 0) orders each XCD's blocks
// j-then-i so every XCD dirties one solid ~27 MB ascending region --
// a fill-like write stream instead of interleaved 512 B strips.
// Proven micro-patterns kept: coalesced staging, SW-swizzled conflict-free
// ds_read_b128, swapped-operand MFMA (D col=j, row=k), plain full-line
// dwordx4 stores. LDS 48 KB -> 3 blocks/CU; acc = 8 floatx4 (per-k-tile
// stores), low VGPR.
__global__ __launch_bounds__(256, 3) void cp_mfma(
    const float* __restrict__ Af, const float* __restrict__ Bf,
    const ushort_t* __restrict__ Cbf, float* __restrict__ out) {
  __shared__ ushort_t Wt[64 * KP];    // 16 KB
  __shared__ ushort_t Ct[128 * KP];   // 32 KB

  // bijective XCD swizzle: 2304 blocks = 8 XCDs x 288
  const int bid = blockIdx.x;
  const int swz = (bid & 7) * 288 + (bid >> 3);
  const int i   = swz / 6;
  const int j0  = (swz % 6) * 64;
  const int t   = threadIdx.x;

  // ---- fold W band [64][128]: 4 threads per j-row, 32 r's each ----
  {
    const int jx = t >> 2;
    const int q  = t & 3;
    const float* __restrict__ arow = Af + (size_t)i * KP + q * 32;
    const float* __restrict__ brow = Bf + (size_t)(j0 + jx) * KP + q * 32;
#pragma unroll
    for (int c = 0; c < 4; ++c) {
      const float4 a0 = *(const float4*)(arow + c * 8);
      const float4 a1 = *(const float4*)(arow + c * 8 + 4);
      const float4 b0 = *(const float4*)(brow + c * 8);
      const float4 b1 = *(const float4*)(brow + c * 8 + 4);
      uint4 wv;
      wv.x = (unsigned)f2bf(a0.x * b0.x) | ((unsigned)f2bf(a0.y * b0.y) << 16);
      wv.y = (unsigned)f2bf(a0.z * b0.z) | ((unsigned)f2bf(a0.w * b0.w) << 16);
      wv.z = (unsigned)f2bf(a1.x * b1.x) | ((unsigned)f2bf(a1.y * b1.y) << 16);
      wv.w = (unsigned)f2bf(a1.z * b1.z) | ((unsigned)f2bf(a1.w * b1.w) << 16);
      *(uint4*)&Wt[SW(jx, q * 4 + c)] = wv;
    }
  }

  const int lane = t & 63;
  const int w    = t >> 6;       // wave owns j-band [j0 + w*16, +16)
  const int m16  = lane & 15;
  const int g    = lane >> 4;
  const int jrow = j0 + w * 16 + m16;
  const size_t obase = (size_t)i * NN * NN + (size_t)jrow * NN;

#pragma unroll 1
  for (int kt = 0; kt < 3; ++kt) {
    __syncthreads();  // kt=0: Wt visible; kt>0: prev MFMA done reading Ct

    // ---- stage C k-tile kt into swizzled LDS (16B chunks) ----
#pragma unroll
    for (int it = 0; it < 8; ++it) {
      const int idx = t + 256 * it;
      const int row = idx >> 4;
      const int ch  = idx & 15;
      *(uint4*)&Ct[SW(row, ch)] =
          *(const uint4*)&Cbf[(size_t)(kt * 128 + row) * KP + ch * 8];
    }
    __syncthreads();

    // acc[kf]: D col = j (m16), D row = k (g*4 + reg)
    floatx4 acc[8];
#pragma unroll
    for (int kf = 0; kf < 8; ++kf) acc[kf] = (floatx4)0.0f;

#pragma unroll
    for (int ks = 0; ks < 4; ++ks) {
      const bf16x8 wfr = *(const bf16x8*)&Wt[SW(w * 16 + m16, ks * 4 + g)];
#pragma unroll
      for (int kf = 0; kf < 8; ++kf) {
        const bf16x8 cf = *(const bf16x8*)&Ct[SW(kf * 16 + m16, ks * 4 + g)];
        acc[kf] = __builtin_amdgcn_mfma_f32_16x16x32_bf16(
            cf, wfr, acc[kf], 0, 0, 0);
      }
    }

    // ---- stores: lane owns out[i, jrow, kt*128 + kf*16 + g*4 .. +3] ----
    const int kb = kt * 128 + g * 4;
#pragma unroll
    for (int kf = 0; kf < 8; ++kf) {
      *(floatx4*)&out[obase + kb + kf * 16] = acc[kf];
    }
  }
}

extern "C" void kernel_launch(void* const* d_in, const int* in_sizes, int n_in,
                              void* d_out, int out_size, void* d_ws, size_t ws_size,
                              hipStream_t stream) {
  const float* A_input = (const float*)d_in[0];
  const float* B_input = (const float*)d_in[1];
  const float* C_input = (const float*)d_in[2];
  const float* A_W1 = (const float*)d_in[3];
  const float* A_b1 = (const float*)d_in[4];
  const float* A_W2 = (const float*)d_in[5];
  const float* A_b2 = (const float*)d_in[6];
  const float* B_W1 = (const float*)d_in[7];
  const float* B_b1 = (const float*)d_in[8];
  const float* B_W2 = (const float*)d_in[9];
  const float* B_b2 = (const float*)d_in[10];
  const float* C_W1 = (const float*)d_in[11];
  const float* C_b1 = (const float*)d_in[12];
  const float* C_W2 = (const float*)d_in[13];
  const float* C_b2 = (const float*)d_in[14];
  const float* C_W3 = (const float*)d_in[15];
  const float* C_b3 = (const float*)d_in[16];

  // ws layout: Af fp32 [384][128] | Bf fp32 [384][128] | Cbf bf16 [384][128]
  float* Af = (float*)d_ws;                       // 196,608 B
  float* Bf = Af + NN * KP;                       // 196,608 B
  ushort_t* Cbf = (ushort_t*)(Bf + NN * KP);      //  98,304 B  (total 480 KB)

  dim3 fgrid(NN, 3);
  factors_kernel<<<fgrid, 256, 0, stream>>>(
      A_input, B_input, C_input,
      A_W1, A_b1, A_W2, A_b2,
      B_W1, B_b1, B_W2, B_b2,
      C_W1, C_b1, C_W2, C_b2, C_W3, C_b3,
      Af, Bf, Cbf);

  // 2304 blocks = (NN/64 j-slabs) x (NN i)
  cp_mfma<<<dim3((NN / 64) * NN), 256, 0, stream>>>(Af, Bf, Cbf, (float*)d_out);
}